// Round 8
// baseline (277.436 us; speedup 1.0000x reference)
//
#include <hip/hip_runtime.h>

// Fixed problem sizes: b=4, c=256, n=4096, cr=32.
#define Bb 4
#define Cc 256
#define Nn 4096
#define CR 32
#define EPS_BN 1e-5f
// Fixed-shift softmax: scores >= 0 (post-ReLU Q,K), bounded << 100, so
// exp(s-20) is exactly softmax-equivalent and overflow/underflow safe.
// K is pre-scaled by log2(e) in qkv, so attn uses exp2(s' - 20*log2e).
#define SHIFT2 28.853900817779268f
#define LOG2E  1.4426950408889634f
#define JSPLIT 4
#define JSL (Nn / JSPLIT)    // 1024 j per attention block
#define TJ 64                // j-tile
#define NTILES (JSL / TJ)    // 16

typedef __attribute__((ext_vector_type(8))) short short8;   // 8 bf16
typedef __attribute__((ext_vector_type(4))) float f32x4;

__device__ inline unsigned int pk2(float a, float b) {
    __bf16 ha = (__bf16)a, hb = (__bf16)b;
    unsigned short ra = __builtin_bit_cast(unsigned short, ha);
    unsigned short rb = __builtin_bit_cast(unsigned short, hb);
    return ((unsigned int)rb << 16) | ra;
}
__device__ inline float blo(unsigned int u) { return __uint_as_float(u << 16); }
__device__ inline float bhi(unsigned int u) { return __uint_as_float(u & 0xffff0000u); }
__device__ inline float ex2(float x) { return __builtin_amdgcn_exp2f(x); }

// ---------------------------------------------------------------------------
// Kernel 0: xT[b][n][c] = x[b][c][n] as split-bf16 (hi + lo planes).
// grid (64, 4, 4), block 256. Transpose reads rotated per-cq: 2-way max (free).
// ---------------------------------------------------------------------------
__global__ __launch_bounds__(256) void xt_kernel(
    const float* __restrict__ x, __bf16* __restrict__ xTh, __bf16* __restrict__ xTl)
{
    __shared__ float sT[64][68];
    const int tid = threadIdx.x;
    const int n0 = blockIdx.x * 64, c0 = blockIdx.y * 64, b = blockIdx.z;
    const int n4 = tid & 15, cr = tid >> 4;
#pragma unroll
    for (int it = 0; it < 4; ++it) {
        int cl = cr + it * 16;
        float4 t = *(const float4*)&x[(size_t)(b * Cc + c0 + cl) * Nn + n0 + n4 * 4];
        *(float4*)&sT[cl][n4 * 4] = t;
    }
    __syncthreads();
    const int nl = tid >> 2, cq = tid & 3;
    float hv[16], lv[16];
#pragma unroll
    for (int ee = 0; ee < 16; ++ee) {
        int e = (ee + 4 * cq) & 15;         // rotation kills 4-way bank conflict
        float v = sT[cq * 16 + e][nl];
        float h = (float)(__bf16)v;
        hv[e] = h; lv[e] = v - h;
    }
    uint4 H0 = { pk2(hv[0],hv[1]), pk2(hv[2],hv[3]), pk2(hv[4],hv[5]), pk2(hv[6],hv[7]) };
    uint4 H1 = { pk2(hv[8],hv[9]), pk2(hv[10],hv[11]), pk2(hv[12],hv[13]), pk2(hv[14],hv[15]) };
    uint4 L0 = { pk2(lv[0],lv[1]), pk2(lv[2],lv[3]), pk2(lv[4],lv[5]), pk2(lv[6],lv[7]) };
    uint4 L1 = { pk2(lv[8],lv[9]), pk2(lv[10],lv[11]), pk2(lv[12],lv[13]), pk2(lv[14],lv[15]) };
    size_t row = (size_t)(b * Nn + n0 + nl) * Cc + c0 + cq * 16;
    *(uint4*)&xTh[row] = H0; *(uint4*)&xTh[row + 8] = H1;
    *(uint4*)&xTl[row] = L0; *(uint4*)&xTl[row + 8] = L1;
}

// ---------------------------------------------------------------------------
// Kernel 1: QKV = BN_ReLU(W x) via MFMA (split-bf16 x => fp32-grade accuracy).
// x-chunks LDS-staged (shared across waves, reg-prefetched). K rows get BN
// scale/bias pre-multiplied by log2(e) so attention can use exp2 directly.
// Outputs Qt/Kt [b][n][32] bf16, Vb [b][c][n] bf16.
// grid (32 n-tiles, 5 row-groups, 4 b), block 256.
// ---------------------------------------------------------------------------
__global__ __launch_bounds__(256) void qkv_kernel(
    const __bf16* __restrict__ xTh, const __bf16* __restrict__ xTl,
    const float* __restrict__ wq, const float* __restrict__ wk, const float* __restrict__ wv,
    const float* __restrict__ bn1s, const float* __restrict__ bn1b, const float* __restrict__ bn1m, const float* __restrict__ bn1v,
    const float* __restrict__ bn2s, const float* __restrict__ bn2b, const float* __restrict__ bn2m, const float* __restrict__ bn2v,
    const float* __restrict__ bn3s, const float* __restrict__ bn3b, const float* __restrict__ bn3m, const float* __restrict__ bn3v,
    __bf16* __restrict__ Qt, __bf16* __restrict__ Kt, __bf16* __restrict__ Vb)
{
    // LDS union: phase1 sW [64][264], phase2 sX [2][128][40], phase3 oT [64][136]
    __shared__ __align__(16) char uL[64 * 264 * 2];
    __bf16* sW = (__bf16*)uL;
    __bf16* sX = (__bf16*)uL;
    __bf16* oT = (__bf16*)uL;

    const int tid = threadIdx.x;
    const int n0 = blockIdx.x * 128, g = blockIdx.y, b = blockIdx.z;
    const int lane = tid & 63, w = tid >> 6;
    const int l15 = lane & 15, l4 = lane >> 4;

    // phase 1: stage W rows (f32 -> bf16), read per-wave A-frags into regs
    {
        int r = tid >> 2, q = tid & 3;
        int R = g * 64 + r;
        const float* src = (R < 32) ? (wq + (size_t)R * Cc)
                         : (R < 64) ? (wk + (size_t)(R - 32) * Cc)
                                    : (wv + (size_t)(R - 64) * Cc);
#pragma unroll
        for (int u8 = 0; u8 < 8; ++u8) {
            float4 a = *(const float4*)&src[q * 64 + u8 * 8];
            float4 c2 = *(const float4*)&src[q * 64 + u8 * 8 + 4];
            uint4 p = { pk2(a.x,a.y), pk2(a.z,a.w), pk2(c2.x,c2.y), pk2(c2.z,c2.w) };
            *(uint4*)&sW[r * 264 + q * 64 + u8 * 8] = p;
        }
    }
    __syncthreads();
    short8 af[8];
#pragma unroll
    for (int kc = 0; kc < 8; ++kc)
        af[kc] = *(const short8*)&sW[(w * 16 + l15) * 264 + kc * 32 + l4 * 8];

    // x chunk loader mapping + prefetch chunk 0
    const int xp = tid >> 7;        // plane 0=hi, 1=lo
    const int xn = tid & 127;       // n row within tile
    const __bf16* xsrc = (xp ? xTl : xTh) + (size_t)(b * Nn + n0 + xn) * Cc;
    uint4 xbuf[4];
#pragma unroll
    for (int s = 0; s < 4; ++s) xbuf[s] = *(const uint4*)&xsrc[s * 8];

    f32x4 acc[8];
#pragma unroll
    for (int z = 0; z < 8; ++z) acc[z] = (f32x4){0.f, 0.f, 0.f, 0.f};

    for (int kc = 0; kc < 8; ++kc) {
        __syncthreads();   // protect prior chunk's sX reads (and af reads at kc=0)
#pragma unroll
        for (int s = 0; s < 4; ++s)
            *(uint4*)&sX[(xp * 128 + xn) * 40 + s * 8] = xbuf[s];
        __syncthreads();
        if (kc + 1 < 8) {
#pragma unroll
            for (int s = 0; s < 4; ++s)
                xbuf[s] = *(const uint4*)&xsrc[(kc + 1) * 32 + s * 8];
        }
#pragma unroll
        for (int nt = 0; nt < 8; ++nt) {
            short8 bh = *(const short8*)&sX[(nt * 16 + l15) * 40 + l4 * 8];
            short8 bl = *(const short8*)&sX[(128 + nt * 16 + l15) * 40 + l4 * 8];
            acc[nt] = __builtin_amdgcn_mfma_f32_16x16x32_bf16(af[kc], bh, acc[nt], 0, 0, 0);
            acc[nt] = __builtin_amdgcn_mfma_f32_16x16x32_bf16(af[kc], bl, acc[nt], 0, 0, 0);
        }
    }

    // BN fold per C-row: R-local = 16w + 4*l4 + r; K rows scaled by log2(e)
    float scl[4], off[4];
#pragma unroll
    for (int r = 0; r < 4; ++r) {
        int R = g * 64 + w * 16 + l4 * 4 + r;
        const float *bs, *bbi, *bm, *bv2; int row;
        if (R < 32)      { row = R;      bs = bn1s; bbi = bn1b; bm = bn1m; bv2 = bn1v; }
        else if (R < 64) { row = R - 32; bs = bn2s; bbi = bn2b; bm = bn2m; bv2 = bn2v; }
        else             { row = R - 64; bs = bn3s; bbi = bn3b; bm = bn3m; bv2 = bn3v; }
        float s = bs[row] * __frsqrt_rn(bv2[row] + EPS_BN);
        float o = bbi[row] - bm[row] * s;
        if (g == 0 && R >= 32) { s *= LOG2E; o *= LOG2E; }   // K pre-scale for exp2
        scl[r] = s; off[r] = o;
    }

    if (g == 0) {
        // Q (w<2) / K (w>=2): direct [n][d] stores, d0 = (w&1)*16 + 4*l4
        __bf16* dst = (w < 2) ? Qt : Kt;
        int d0 = (w & 1) * 16 + l4 * 4;
#pragma unroll
        for (int nt = 0; nt < 8; ++nt) {
            f32x4 a = acc[nt];
            float e0 = fmaxf(fmaf(a.x, scl[0], off[0]), 0.f);
            float e1 = fmaxf(fmaf(a.y, scl[1], off[1]), 0.f);
            float e2 = fmaxf(fmaf(a.z, scl[2], off[2]), 0.f);
            float e3 = fmaxf(fmaf(a.w, scl[3], off[3]), 0.f);
            uint2 p = { pk2(e0, e1), pk2(e2, e3) };
            int n = n0 + nt * 16 + l15;
            *(uint2*)&dst[(size_t)(b * Nn + n) * CR + d0] = p;
        }
    } else {
        // V: transpose via LDS (reuse union), then coalesced [c][n] stores
        __syncthreads();
#pragma unroll
        for (int nt = 0; nt < 8; ++nt) {
            f32x4 a = acc[nt];
            float e[4];
            e[0] = fmaxf(fmaf(a.x, scl[0], off[0]), 0.f);
            e[1] = fmaxf(fmaf(a.y, scl[1], off[1]), 0.f);
            e[2] = fmaxf(fmaf(a.z, scl[2], off[2]), 0.f);
            e[3] = fmaxf(fmaf(a.w, scl[3], off[3]), 0.f);
#pragma unroll
            for (int r = 0; r < 4; ++r)
                oT[(w * 16 + l4 * 4 + r) * 136 + nt * 16 + l15] = (__bf16)e[r];
        }
        __syncthreads();
        int rr = tid >> 2, qq = tid & 3;
        size_t vrow = (size_t)(b * Cc + (g - 1) * 64 + rr) * Nn + n0 + qq * 32;
#pragma unroll
        for (int e8 = 0; e8 < 4; ++e8)
            *(uint4*)&Vb[vrow + e8 * 8] = *(const uint4*)&oT[rr * 136 + qq * 32 + e8 * 8];
    }
}

// ---------------------------------------------------------------------------
// Kernel 2: attention partials, j-split = 4, XCD-swizzled 1D grid: id&7 maps
// (js, b-half) to one XCD so each XCD's L2 holds its ~1 MB V working set.
// V B-frags direct from (local) L2. Partials in raw MFMA C-layout.
// grid 1024 (= JSPLIT*Bb*Nn/64), block 256 (4 waves).
// ---------------------------------------------------------------------------
__global__ __launch_bounds__(256) void attn_kernel(
    const __bf16* __restrict__ Qt, const __bf16* __restrict__ Kt,
    const __bf16* __restrict__ Vb,
    __bf16* __restrict__ PO, float* __restrict__ PL)
{
    __shared__ __align__(16) __bf16 sQ[64 * 40];   // 5.1 KB
    __shared__ __align__(16) __bf16 sP[64 * 72];   // 9.2 KB
    __shared__ __align__(16) float  sL[4][64];     // 1 KB

    const int tid = threadIdx.x, lane = tid & 63, w = tid >> 6;
    // swizzled decode: xcd = id&7 = (js, b-half); k = id>>3 = (b-low, i-block)
    const int id = blockIdx.x;
    const int xcd = id & 7, k = id >> 3;
    const int js = xcd >> 1;
    const int b  = (xcd & 1) * 2 + (k & 1);
    const int iblk = k >> 1;
    const int i0 = iblk * 64;
    const int l15 = lane & 15, l4 = lane >> 4;

    // stage Q tile [i][d], then per-wave B-frags (held all kernel)
    {
        int i = tid >> 2, o = tid & 3;
        *(uint4*)&sQ[i * 40 + o * 8] =
            *(const uint4*)&Qt[(size_t)(b * Nn + i0 + i) * CR + o * 8];
    }
    __syncthreads();
    short8 qf[4];
#pragma unroll
    for (int it = 0; it < 4; ++it)
        qf[it] = *(const short8*)&sQ[(it * 16 + l15) * 40 + l4 * 8];

    f32x4 oacc[16];
#pragma unroll
    for (int z = 0; z < 16; ++z) oacc[z] = (f32x4){0.f, 0.f, 0.f, 0.f};
    float lp[4] = {0.f, 0.f, 0.f, 0.f};

    const size_t jb = (size_t)js * JSL;
    short8 kf = *(const short8*)&Kt[(size_t)(b * Nn + jb + 16 * w + l15) * CR + l4 * 8];

    for (int t = 0; t < NTILES; ++t) {
        const size_t j0 = jb + (size_t)t * TJ;

        // issue this tile's V B-frag loads (local-L2 hit; consumed after barrier A)
        short8 vf[8];
#pragma unroll
        for (int u = 0; u < 8; ++u) {
            int jh = u >> 2, ct = u & 3;
            int c = w * 64 + ct * 16 + l15;
            vf[u] = *(const short8*)&Vb[(size_t)(b * Cc + c) * Nn + j0 + (jh * 4 + l4) * 8];
        }

        // scores: wave w owns j-slice [16w,16w+16): S^T = K·Q^T, exp2, pack -> sP
#pragma unroll
        for (int it = 0; it < 4; ++it) {
            f32x4 c0 = (f32x4){0.f, 0.f, 0.f, 0.f};
            c0 = __builtin_amdgcn_mfma_f32_16x16x32_bf16(kf, qf[it], c0, 0, 0, 0);
            float e0 = ex2(c0.x - SHIFT2);
            float e1 = ex2(c0.y - SHIFT2);
            float e2 = ex2(c0.z - SHIFT2);
            float e3 = ex2(c0.w - SHIFT2);
            lp[it] += (e0 + e1) + (e2 + e3);
            uint2 p2 = { pk2(e0, e1), pk2(e2, e3) };
            *(uint2*)&sP[(it * 16 + l15) * 72 + w * 16 + l4 * 4] = p2;
        }
        __syncthreads();   // barrier A: sP visible to all waves

        // prefetch next tile's K A-frag during PV
        if (t + 1 < NTILES)
            kf = *(const short8*)&Kt[(size_t)(b * Nn + j0 + TJ + 16 * w + l15) * CR + l4 * 8];

        // PV: wave w owns c-slice [64w,64w+64)
#pragma unroll
        for (int jh = 0; jh < 2; ++jh) {
            short8 pf[4];
#pragma unroll
            for (int it = 0; it < 4; ++it)
                pf[it] = *(const short8*)&sP[(it * 16 + l15) * 72 + jh * 32 + l4 * 8];
#pragma unroll
            for (int ct = 0; ct < 4; ++ct) {
#pragma unroll
                for (int it = 0; it < 4; ++it)
                    oacc[it * 4 + ct] = __builtin_amdgcn_mfma_f32_16x16x32_bf16(
                        pf[it], vf[jh * 4 + ct], oacc[it * 4 + ct], 0, 0, 0);
            }
        }
        __syncthreads();   // barrier B: protect sP for next tile
    }

    // partial row sums l -> PL
#pragma unroll
    for (int it = 0; it < 4; ++it) {
        float v = lp[it];
        v += __shfl_xor(v, 16);
        v += __shfl_xor(v, 32);
        if (lane < 16) sL[w][it * 16 + lane] = v;
    }
    __syncthreads();
    if (tid < 64)
        PL[(size_t)(js * Bb + b) * Nn + i0 + tid] =
            sL[0][tid] + sL[1][tid] + sL[2][tid] + sL[3][tid];

    // store partials in raw C-layout, bf16-packed (4 consecutive i per uint2)
    const size_t base = (size_t)((js * Bb + b) * (Nn / 64) + iblk) * 16384;
#pragma unroll
    for (int it = 0; it < 4; ++it)
#pragma unroll
        for (int ct = 0; ct < 4; ++ct) {
            f32x4 a = oacc[it * 4 + ct];
            uint2 p = { pk2(a.x, a.y), pk2(a.z, a.w) };
            *(uint2*)&PO[base + (size_t)((((w * 4 + it) * 4 + ct) * 64 + lane)) * 4] = p;
        }
}

// ---------------------------------------------------------------------------
// Kernel 3: sum 4 j-split partials, normalize, transpose via LDS,
// out = gamma * o + x. grid (64 i-tiles, 4 c-quarters, 4 b), block 256.
// ---------------------------------------------------------------------------
__global__ __launch_bounds__(256) void reduce_kernel(
    const __bf16* __restrict__ PO, const float* __restrict__ PL,
    const float* __restrict__ x, const float* __restrict__ gamma,
    float* __restrict__ out)
{
    __shared__ __align__(16) float oT[64 * 68];   // 17.4 KB
    __shared__ float sLinv[64];

    const int tid = threadIdx.x;
    const int iblk = blockIdx.x, wq = blockIdx.y, b = blockIdx.z;
    const int i0 = iblk * 64;
    const int lane = tid & 63, ct = tid >> 6, l15 = lane & 15, l4 = lane >> 4;

    if (tid < 64) {
        float l = 0.f;
#pragma unroll
        for (int js = 0; js < JSPLIT; ++js)
            l += PL[(size_t)(js * Bb + b) * Nn + i0 + tid];
        sLinv[tid] = 1.0f / l;
    }

    float o[4][4];
#pragma unroll
    for (int it = 0; it < 4; ++it) {
        o[it][0] = o[it][1] = o[it][2] = o[it][3] = 0.f;
#pragma unroll
        for (int js = 0; js < JSPLIT; ++js) {
            size_t base = (size_t)((js * Bb + b) * (Nn / 64) + iblk) * 16384;
            uint2 v = *(const uint2*)&PO[base + (size_t)((((wq * 4 + it) * 4 + ct) * 64 + lane)) * 4];
            o[it][0] += blo(v.x); o[it][1] += bhi(v.x);
            o[it][2] += blo(v.y); o[it][3] += bhi(v.y);
        }
    }

    // transpose into [c_local][i]
    const int cl = ct * 16 + l15;
#pragma unroll
    for (int it = 0; it < 4; ++it) {
        float4 t4 = { o[it][0], o[it][1], o[it][2], o[it][3] };
        *(float4*)&oT[cl * 68 + it * 16 + l4 * 4] = t4;
    }
    __syncthreads();

    const float g = gamma[0];
    const int c_l = tid >> 2, icol = (tid & 3) * 16;
    const int cg = wq * 64 + c_l;
    const size_t gb = (size_t)(b * Cc + cg) * Nn + i0 + icol;
#pragma unroll
    for (int k4 = 0; k4 < 4; ++k4) {
        float4 ov = *(const float4*)&oT[c_l * 68 + icol + k4 * 4];
        float4 li = *(const float4*)&sLinv[icol + k4 * 4];
        float4 xv = *(const float4*)&x[gb + k4 * 4];
        float4 res;
        res.x = fmaf(g, ov.x * li.x, xv.x);
        res.y = fmaf(g, ov.y * li.y, xv.y);
        res.z = fmaf(g, ov.z * li.z, xv.z);
        res.w = fmaf(g, ov.w * li.w, xv.w);
        *(float4*)&out[gb + k4 * 4] = res;
    }
}

// ---------------------------------------------------------------------------
extern "C" void kernel_launch(void* const* d_in, const int* in_sizes, int n_in,
                              void* d_out, int out_size, void* d_ws, size_t ws_size,
                              hipStream_t stream)
{
    const float* x    = (const float*)d_in[0];
    const float* wq   = (const float*)d_in[1];
    const float* wk   = (const float*)d_in[2];
    const float* wv   = (const float*)d_in[3];
    const float* bn1s = (const float*)d_in[4];
    const float* bn1b = (const float*)d_in[5];
    const float* bn1m = (const float*)d_in[6];
    const float* bn1v = (const float*)d_in[7];
    const float* bn2s = (const float*)d_in[8];
    const float* bn2b = (const float*)d_in[9];
    const float* bn2m = (const float*)d_in[10];
    const float* bn2v = (const float*)d_in[11];
    const float* bn3s = (const float*)d_in[12];
    const float* bn3b = (const float*)d_in[13];
    const float* bn3m = (const float*)d_in[14];
    const float* bn3v = (const float*)d_in[15];
    const float* gmm  = (const float*)d_in[16];
    float* out = (float*)d_out;

    // workspace layout (bytes):
    //  [Qt 1M][Kt 1M][Vb 8M][big region: xTh+xTl (16.8M) during QKV, then PO 33.6M + PL]
    char* ws = (char*)d_ws;
    __bf16* Qt  = (__bf16*)(ws);
    __bf16* Kt  = (__bf16*)(ws + (1u << 20));
    __bf16* Vb  = (__bf16*)(ws + (2u << 20));
    char*   big = ws + (10u << 20);
    __bf16* xTh = (__bf16*)big;
    __bf16* xTl = (__bf16*)(big + 8388608);
    __bf16* PO  = (__bf16*)big;                  // reuses xT space after QKV
    float*  PL  = (float*)(big + 33554432);

    xt_kernel<<<dim3(Nn / 64, Cc / 64, Bb), 256, 0, stream>>>(x, xTh, xTl);

    qkv_kernel<<<dim3(Nn / 128, 5, Bb), 256, 0, stream>>>(
        xTh, xTl, wq, wk, wv,
        bn1s, bn1b, bn1m, bn1v,
        bn2s, bn2b, bn2m, bn2v,
        bn3s, bn3b, bn3m, bn3v,
        Qt, Kt, Vb);

    attn_kernel<<<dim3(JSPLIT * Bb * (Nn / 64)), 256, 0, stream>>>(Qt, Kt, Vb, PO, PL);

    reduce_kernel<<<dim3(Nn / 64, 4, Bb), 256, 0, stream>>>(PO, PL, x, gmm, out);
}

// Round 9
// 211.755 us; speedup vs baseline: 1.3102x; 1.3102x over previous
//
#include <hip/hip_runtime.h>

// Fixed problem sizes: b=4, c=256, n=4096, cr=32.
#define Bb 4
#define Cc 256
#define Nn 4096
#define CR 32
#define EPS_BN 1e-5f
// Fixed-shift softmax: scores >= 0 (post-ReLU Q,K), bounded << 100, so
// exp(s-20) is exactly softmax-equivalent and overflow/underflow safe.
// K is pre-scaled by log2(e) in qkv, so attn uses exp2(s' - 20*log2e).
#define SHIFT2 28.853900817779268f
#define LOG2E  1.4426950408889634f
#define JSPLIT 4
#define JSL (Nn / JSPLIT)    // 1024 j per attention block
#define TJ 64                // j-tile
#define NTILES (JSL / TJ)    // 16

typedef __attribute__((ext_vector_type(8))) short short8;   // 8 bf16
typedef __attribute__((ext_vector_type(4))) float f32x4;

__device__ inline unsigned int pk2(float a, float b) {
    __bf16 ha = (__bf16)a, hb = (__bf16)b;
    unsigned short ra = __builtin_bit_cast(unsigned short, ha);
    unsigned short rb = __builtin_bit_cast(unsigned short, hb);
    return ((unsigned int)rb << 16) | ra;
}
__device__ inline float blo(unsigned int u) { return __uint_as_float(u << 16); }
__device__ inline float bhi(unsigned int u) { return __uint_as_float(u & 0xffff0000u); }
__device__ inline float ex2(float x) { return __builtin_amdgcn_exp2f(x); }

// ---------------------------------------------------------------------------
// Kernel 1: QKV = BN_ReLU(W x) via MFMA, split-bf16 x (fp32-grade accuracy),
// reading x DIRECTLY (coalesced). Per-wave-private LDS transpose => the K-loop
// has NO __syncthreads (only same-wave waitcnts). W staged once in LDS in
// frag-major layout (conflict-free b128 A-frag reads).
// Wave w owns n-slice [32w,32w+32) of the 128-n tile, all 64 output rows.
// Outputs Qt/Kt [b][n][32] bf16 (K pre-scaled by log2e), Vb [b][c][n] bf16.
// grid (32 n-tiles, 5 row-groups, 4 b), block 256.
// ---------------------------------------------------------------------------
__global__ __launch_bounds__(256) void qkv_kernel(
    const float* __restrict__ x,
    const float* __restrict__ wq, const float* __restrict__ wk, const float* __restrict__ wv,
    const float* __restrict__ bn1s, const float* __restrict__ bn1b, const float* __restrict__ bn1m, const float* __restrict__ bn1v,
    const float* __restrict__ bn2s, const float* __restrict__ bn2b, const float* __restrict__ bn2m, const float* __restrict__ bn2v,
    const float* __restrict__ bn3s, const float* __restrict__ bn3b, const float* __restrict__ bn3m, const float* __restrict__ bn3v,
    __bf16* __restrict__ Qt, __bf16* __restrict__ Kt, __bf16* __restrict__ Vb)
{
    // F: frag-major W, [kc*4+mt][lane][8 bf16] = 32 KB (reused as oT in V epi)
    __shared__ __align__(16) __bf16 F[16384];
    __shared__ __align__(16) float  sXf[4][32 * 40];       // per-wave [c][40] f32
    __shared__ __align__(16) __bf16 sXt[4][2][32 * 40];    // per-wave [plane][n][40]

    const int tid = threadIdx.x;
    const int n0 = blockIdx.x * 128, g = blockIdx.y, b = blockIdx.z;
    const int lane = tid & 63, w = tid >> 6;
    const int l15 = lane & 15, l4 = lane >> 4;

    // ---- phase 1: stage W in frag-major bf16 layout ----
    {
        int r = tid >> 2, q = tid & 3;       // row r (64), c-quarter q (64 c)
        int R = g * 64 + r;
        const float* src = (R < 32) ? (wq + (size_t)R * Cc)
                         : (R < 64) ? (wk + (size_t)(R - 32) * Cc)
                                    : (wv + (size_t)(R - 64) * Cc);
        int mt = r >> 4, l15r = r & 15;
#pragma unroll
        for (int u8 = 0; u8 < 8; ++u8) {
            float4 a = *(const float4*)&src[q * 64 + u8 * 8];
            float4 c2 = *(const float4*)&src[q * 64 + u8 * 8 + 4];
            uint4 p = { pk2(a.x,a.y), pk2(a.z,a.w), pk2(c2.x,c2.y), pk2(c2.z,c2.w) };
            int kc = 2 * q + (u8 >> 2), l4k = u8 & 3;
            *(uint4*)&F[(((kc * 4 + mt) * 64 + l4k * 16 + l15r)) * 8] = p;
        }
    }

    // per-wave LDS pointers
    float*  sXfw  = &sXf[w][0];
    __bf16* sXtw0 = &sXt[w][0][0];
    __bf16* sXtw1 = &sXt[w][1][0];

    // global loader mapping (wave-private): cr = c-row (8), nq = n-quad (8)
    const int cr = lane >> 3, nq = lane & 7;
    const float* xbase = x + (size_t)(b * Cc + cr) * Nn + n0 + w * 32 + nq * 4;

    // prefetch chunk 0
    float4 xg[4];
#pragma unroll
    for (int it = 0; it < 4; ++it)
        xg[it] = *(const float4*)&xbase[(size_t)(it * 8) * Nn];

    __syncthreads();   // F staged; af reads below are safe

    f32x4 acc[4][2];
#pragma unroll
    for (int mt = 0; mt < 4; ++mt)
#pragma unroll
        for (int nt = 0; nt < 2; ++nt) acc[mt][nt] = (f32x4){0.f, 0.f, 0.f, 0.f};

    for (int kc = 0; kc < 8; ++kc) {
        // stage this chunk into wave-private sXf [c][n]
#pragma unroll
        for (int it = 0; it < 4; ++it)
            *(float4*)&sXfw[(it * 8 + cr) * 40 + nq * 4] = xg[it];

        // prefetch next chunk (overlaps transpose + MFMA)
        if (kc + 1 < 8) {
#pragma unroll
            for (int it = 0; it < 4; ++it)
                xg[it] = *(const float4*)&xbase[(size_t)((kc + 1) * 32 + it * 8) * Nn];
        }

        // wave-private transpose + hi/lo split: 2 slots of (n, 8 c) per lane
#pragma unroll
        for (int s = 0; s < 2; ++s) {
            int n = lane & 31, c0 = (lane >> 5) * 8 + s * 16;
            float h[8], lo[8];
#pragma unroll
            for (int j = 0; j < 8; ++j) {
                float v = sXfw[(c0 + j) * 40 + n];
                float hh = (float)(__bf16)v;
                h[j] = hh; lo[j] = v - hh;
            }
            uint4 H = { pk2(h[0],h[1]), pk2(h[2],h[3]), pk2(h[4],h[5]), pk2(h[6],h[7]) };
            uint4 L = { pk2(lo[0],lo[1]), pk2(lo[2],lo[3]), pk2(lo[4],lo[5]), pk2(lo[6],lo[7]) };
            *(uint4*)&sXtw0[n * 40 + c0] = H;
            *(uint4*)&sXtw1[n * 40 + c0] = L;
        }

        // B-frags (wave-private rows), A-frags from F, 16 MFMA
        short8 bh[2], bl[2];
#pragma unroll
        for (int nt = 0; nt < 2; ++nt) {
            bh[nt] = *(const short8*)&sXtw0[(nt * 16 + l15) * 40 + l4 * 8];
            bl[nt] = *(const short8*)&sXtw1[(nt * 16 + l15) * 40 + l4 * 8];
        }
#pragma unroll
        for (int mt = 0; mt < 4; ++mt) {
            short8 af = *(const short8*)&F[((kc * 4 + mt) * 64 + lane) * 8];
#pragma unroll
            for (int nt = 0; nt < 2; ++nt) {
                acc[mt][nt] = __builtin_amdgcn_mfma_f32_16x16x32_bf16(af, bh[nt], acc[mt][nt], 0, 0, 0);
                acc[mt][nt] = __builtin_amdgcn_mfma_f32_16x16x32_bf16(af, bl[nt], acc[mt][nt], 0, 0, 0);
            }
        }
    }

    // ---- epilogue: BN fold + ReLU + store ----
    if (g == 0) {
        // Q (mt<2) / K (mt>=2, log2e-scaled): [n][d] uint2 stores
#pragma unroll
        for (int mt = 0; mt < 4; ++mt) {
            float scl[4], off[4];
#pragma unroll
            for (int r = 0; r < 4; ++r) {
                int R = mt * 16 + l4 * 4 + r;
                float s, o;
                if (R < 32) {
                    s = bn1s[R] * __frsqrt_rn(bn1v[R] + EPS_BN);
                    o = bn1b[R] - bn1m[R] * s;
                } else {
                    int row = R - 32;
                    s = bn2s[row] * __frsqrt_rn(bn2v[row] + EPS_BN);
                    o = bn2b[row] - bn2m[row] * s;
                    s *= LOG2E; o *= LOG2E;
                }
                scl[r] = s; off[r] = o;
            }
            __bf16* dst = (mt < 2) ? Qt : Kt;
            int d0 = (mt & 1) * 16 + l4 * 4;
#pragma unroll
            for (int nt = 0; nt < 2; ++nt) {
                f32x4 a = acc[mt][nt];
                float e0 = fmaxf(fmaf(a.x, scl[0], off[0]), 0.f);
                float e1 = fmaxf(fmaf(a.y, scl[1], off[1]), 0.f);
                float e2 = fmaxf(fmaf(a.z, scl[2], off[2]), 0.f);
                float e3 = fmaxf(fmaf(a.w, scl[3], off[3]), 0.f);
                uint2 p = { pk2(e0, e1), pk2(e2, e3) };
                int n = n0 + w * 32 + nt * 16 + l15;
                *(uint2*)&dst[(size_t)(b * Nn + n) * CR + d0] = p;
            }
        }
    } else {
        // V: transpose via LDS (reuse F region), coalesced [c][n] stores
        __bf16* oT = F;    // [64 rows][136 n]
        __syncthreads();   // all waves done reading F
#pragma unroll
        for (int mt = 0; mt < 4; ++mt) {
            float scl[4], off[4];
#pragma unroll
            for (int r = 0; r < 4; ++r) {
                int row = (g - 1) * 64 + mt * 16 + l4 * 4 + r;
                float s = bn3s[row] * __frsqrt_rn(bn3v[row] + EPS_BN);
                scl[r] = s; off[r] = bn3b[row] - bn3m[row] * s;
            }
#pragma unroll
            for (int nt = 0; nt < 2; ++nt) {
                f32x4 a = acc[mt][nt];
                float e[4];
                e[0] = fmaxf(fmaf(a.x, scl[0], off[0]), 0.f);
                e[1] = fmaxf(fmaf(a.y, scl[1], off[1]), 0.f);
                e[2] = fmaxf(fmaf(a.z, scl[2], off[2]), 0.f);
                e[3] = fmaxf(fmaf(a.w, scl[3], off[3]), 0.f);
                int ncol = w * 32 + nt * 16 + l15;
#pragma unroll
                for (int r = 0; r < 4; ++r)
                    oT[(mt * 16 + l4 * 4 + r) * 136 + ncol] = (__bf16)e[r];
            }
        }
        __syncthreads();
        int rr = tid >> 2, qq = tid & 3;
        size_t vrow = (size_t)(b * Cc + (g - 1) * 64 + rr) * Nn + n0 + qq * 32;
#pragma unroll
        for (int e8 = 0; e8 < 4; ++e8)
            *(uint4*)&Vb[vrow + e8 * 8] = *(const uint4*)&oT[rr * 136 + qq * 32 + e8 * 8];
    }
}

// ---------------------------------------------------------------------------
// Kernel 2: attention partials, j-split = 4 (R5-proven grid mapping).
// V B-frags direct from L2/L3. Partials in raw MFMA C-layout.
// grid (64 i-tiles, 4 js, 4 b) = 1024 blocks, block 256 (4 waves).
// ---------------------------------------------------------------------------
__global__ __launch_bounds__(256) void attn_kernel(
    const __bf16* __restrict__ Qt, const __bf16* __restrict__ Kt,
    const __bf16* __restrict__ Vb,
    __bf16* __restrict__ PO, float* __restrict__ PL)
{
    __shared__ __align__(16) __bf16 sQ[64 * 40];   // 5.1 KB
    __shared__ __align__(16) __bf16 sP[64 * 72];   // 9.2 KB
    __shared__ __align__(16) float  sL[4][64];     // 1 KB

    const int tid = threadIdx.x, lane = tid & 63, w = tid >> 6;
    const int b = blockIdx.z, js = blockIdx.y, iblk = blockIdx.x;
    const int i0 = iblk * 64;
    const int l15 = lane & 15, l4 = lane >> 4;

    // stage Q tile [i][d], then per-wave B-frags (held all kernel)
    {
        int i = tid >> 2, o = tid & 3;
        *(uint4*)&sQ[i * 40 + o * 8] =
            *(const uint4*)&Qt[(size_t)(b * Nn + i0 + i) * CR + o * 8];
    }
    __syncthreads();
    short8 qf[4];
#pragma unroll
    for (int it = 0; it < 4; ++it)
        qf[it] = *(const short8*)&sQ[(it * 16 + l15) * 40 + l4 * 8];

    f32x4 oacc[16];
#pragma unroll
    for (int z = 0; z < 16; ++z) oacc[z] = (f32x4){0.f, 0.f, 0.f, 0.f};
    float lp[4] = {0.f, 0.f, 0.f, 0.f};

    const size_t jb = (size_t)js * JSL;
    short8 kf = *(const short8*)&Kt[(size_t)(b * Nn + jb + 16 * w + l15) * CR + l4 * 8];

    for (int t = 0; t < NTILES; ++t) {
        const size_t j0 = jb + (size_t)t * TJ;

        // issue this tile's V B-frag loads (consumed after barrier A)
        short8 vf[8];
#pragma unroll
        for (int u = 0; u < 8; ++u) {
            int jh = u >> 2, ct = u & 3;
            int c = w * 64 + ct * 16 + l15;
            vf[u] = *(const short8*)&Vb[(size_t)(b * Cc + c) * Nn + j0 + (jh * 4 + l4) * 8];
        }

        // scores: wave w owns j-slice [16w,16w+16): S^T = K·Q^T, exp2, pack -> sP
#pragma unroll
        for (int it = 0; it < 4; ++it) {
            f32x4 c0 = (f32x4){0.f, 0.f, 0.f, 0.f};
            c0 = __builtin_amdgcn_mfma_f32_16x16x32_bf16(kf, qf[it], c0, 0, 0, 0);
            float e0 = ex2(c0.x - SHIFT2);
            float e1 = ex2(c0.y - SHIFT2);
            float e2 = ex2(c0.z - SHIFT2);
            float e3 = ex2(c0.w - SHIFT2);
            lp[it] += (e0 + e1) + (e2 + e3);
            uint2 p2 = { pk2(e0, e1), pk2(e2, e3) };
            *(uint2*)&sP[(it * 16 + l15) * 72 + w * 16 + l4 * 4] = p2;
        }
        __syncthreads();   // barrier A: sP visible to all waves

        // prefetch next tile's K A-frag during PV
        if (t + 1 < NTILES)
            kf = *(const short8*)&Kt[(size_t)(b * Nn + j0 + TJ + 16 * w + l15) * CR + l4 * 8];

        // PV: wave w owns c-slice [64w,64w+64)
#pragma unroll
        for (int jh = 0; jh < 2; ++jh) {
            short8 pf[4];
#pragma unroll
            for (int it = 0; it < 4; ++it)
                pf[it] = *(const short8*)&sP[(it * 16 + l15) * 72 + jh * 32 + l4 * 8];
#pragma unroll
            for (int ct = 0; ct < 4; ++ct) {
#pragma unroll
                for (int it = 0; it < 4; ++it)
                    oacc[it * 4 + ct] = __builtin_amdgcn_mfma_f32_16x16x32_bf16(
                        pf[it], vf[jh * 4 + ct], oacc[it * 4 + ct], 0, 0, 0);
            }
        }
        __syncthreads();   // barrier B: protect sP for next tile
    }

    // partial row sums l -> PL
#pragma unroll
    for (int it = 0; it < 4; ++it) {
        float v = lp[it];
        v += __shfl_xor(v, 16);
        v += __shfl_xor(v, 32);
        if (lane < 16) sL[w][it * 16 + lane] = v;
    }
    __syncthreads();
    if (tid < 64)
        PL[(size_t)(js * Bb + b) * Nn + i0 + tid] =
            sL[0][tid] + sL[1][tid] + sL[2][tid] + sL[3][tid];

    // store partials in raw C-layout, bf16-packed (4 consecutive i per uint2)
    const size_t base = (size_t)((js * Bb + b) * (Nn / 64) + iblk) * 16384;
#pragma unroll
    for (int it = 0; it < 4; ++it)
#pragma unroll
        for (int ct = 0; ct < 4; ++ct) {
            f32x4 a = oacc[it * 4 + ct];
            uint2 p = { pk2(a.x, a.y), pk2(a.z, a.w) };
            *(uint2*)&PO[base + (size_t)((((w * 4 + it) * 4 + ct) * 64 + lane)) * 4] = p;
        }
}

// ---------------------------------------------------------------------------
// Kernel 3: sum 4 j-split partials, normalize, transpose via LDS,
// out = gamma * o + x. grid (64 i-tiles, 4 c-quarters, 4 b), block 256.
// ---------------------------------------------------------------------------
__global__ __launch_bounds__(256) void reduce_kernel(
    const __bf16* __restrict__ PO, const float* __restrict__ PL,
    const float* __restrict__ x, const float* __restrict__ gamma,
    float* __restrict__ out)
{
    __shared__ __align__(16) float oT[64 * 68];   // 17.4 KB
    __shared__ float sLinv[64];

    const int tid = threadIdx.x;
    const int iblk = blockIdx.x, wq = blockIdx.y, b = blockIdx.z;
    const int i0 = iblk * 64;
    const int lane = tid & 63, ct = tid >> 6, l15 = lane & 15, l4 = lane >> 4;

    if (tid < 64) {
        float l = 0.f;
#pragma unroll
        for (int js = 0; js < JSPLIT; ++js)
            l += PL[(size_t)(js * Bb + b) * Nn + i0 + tid];
        sLinv[tid] = 1.0f / l;
    }

    float o[4][4];
#pragma unroll
    for (int it = 0; it < 4; ++it) {
        o[it][0] = o[it][1] = o[it][2] = o[it][3] = 0.f;
#pragma unroll
        for (int js = 0; js < JSPLIT; ++js) {
            size_t base = (size_t)((js * Bb + b) * (Nn / 64) + iblk) * 16384;
            uint2 v = *(const uint2*)&PO[base + (size_t)((((wq * 4 + it) * 4 + ct) * 64 + lane)) * 4];
            o[it][0] += blo(v.x); o[it][1] += bhi(v.x);
            o[it][2] += blo(v.y); o[it][3] += bhi(v.y);
        }
    }

    // transpose into [c_local][i]
    const int cl = ct * 16 + l15;
#pragma unroll
    for (int it = 0; it < 4; ++it) {
        float4 t4 = { o[it][0], o[it][1], o[it][2], o[it][3] };
        *(float4*)&oT[cl * 68 + it * 16 + l4 * 4] = t4;
    }
    __syncthreads();

    const float g = gamma[0];
    const int c_l = tid >> 2, icol = (tid & 3) * 16;
    const int cg = wq * 64 + c_l;
    const size_t gb = (size_t)(b * Cc + cg) * Nn + i0 + icol;
#pragma unroll
    for (int k4 = 0; k4 < 4; ++k4) {
        float4 ov = *(const float4*)&oT[c_l * 68 + icol + k4 * 4];
        float4 li = *(const float4*)&sLinv[icol + k4 * 4];
        float4 xv = *(const float4*)&x[gb + k4 * 4];
        float4 res;
        res.x = fmaf(g, ov.x * li.x, xv.x);
        res.y = fmaf(g, ov.y * li.y, xv.y);
        res.z = fmaf(g, ov.z * li.z, xv.z);
        res.w = fmaf(g, ov.w * li.w, xv.w);
        *(float4*)&out[gb + k4 * 4] = res;
    }
}

// ---------------------------------------------------------------------------
extern "C" void kernel_launch(void* const* d_in, const int* in_sizes, int n_in,
                              void* d_out, int out_size, void* d_ws, size_t ws_size,
                              hipStream_t stream)
{
    const float* x    = (const float*)d_in[0];
    const float* wq   = (const float*)d_in[1];
    const float* wk   = (const float*)d_in[2];
    const float* wv   = (const float*)d_in[3];
    const float* bn1s = (const float*)d_in[4];
    const float* bn1b = (const float*)d_in[5];
    const float* bn1m = (const float*)d_in[6];
    const float* bn1v = (const float*)d_in[7];
    const float* bn2s = (const float*)d_in[8];
    const float* bn2b = (const float*)d_in[9];
    const float* bn2m = (const float*)d_in[10];
    const float* bn2v = (const float*)d_in[11];
    const float* bn3s = (const float*)d_in[12];
    const float* bn3b = (const float*)d_in[13];
    const float* bn3m = (const float*)d_in[14];
    const float* bn3v = (const float*)d_in[15];
    const float* gmm  = (const float*)d_in[16];
    float* out = (float*)d_out;

    // workspace layout (bytes): [Qt 1M][Kt 1M][Vb 8M][PO 33.6M @ +10M][PL]
    char* ws = (char*)d_ws;
    __bf16* Qt  = (__bf16*)(ws);
    __bf16* Kt  = (__bf16*)(ws + (1u << 20));
    __bf16* Vb  = (__bf16*)(ws + (2u << 20));
    char*   big = ws + (10u << 20);
    __bf16* PO  = (__bf16*)big;
    float*  PL  = (float*)(big + 33554432);

    qkv_kernel<<<dim3(Nn / 128, 5, Bb), 256, 0, stream>>>(
        x, wq, wk, wv,
        bn1s, bn1b, bn1m, bn1v,
        bn2s, bn2b, bn2m, bn2v,
        bn3s, bn3b, bn3m, bn3v,
        Qt, Kt, Vb);

    attn_kernel<<<dim3(Nn / 64, JSPLIT, Bb), 256, 0, stream>>>(Qt, Kt, Vb, PO, PL);

    reduce_kernel<<<dim3(Nn / 64, 4, Bb), 256, 0, stream>>>(PO, PL, x, gmm, out);
}